// Round 5
// baseline (332.420 us; speedup 1.0000x reference)
//
#include <hip/hip_runtime.h>
#include <hip/hip_bf16.h>

#define SEQ   80
#define BATCH 32768
#define HID   10

typedef unsigned int uint;
typedef unsigned short ushort;

#define SIG_SCALE  (-1.44269504f)
#define TANH_SCALE (-2.88539008f)

__device__ __forceinline__ float fast_rcp(float x) { return __builtin_amdgcn_rcpf(x); }
__device__ __forceinline__ float fast_exp2(float x) { return __builtin_amdgcn_exp2f(x); }
__device__ __forceinline__ float fast_tanh(float x) {
    return 2.0f * fast_rcp(1.0f + fast_exp2(TANH_SCALE * x)) - 1.0f;
}
__device__ __forceinline__ ushort bf16bits(float v) {
    __hip_bfloat16 h = __float2bfloat16(v);
    return *reinterpret_cast<ushort*>(&h);
}
__device__ __forceinline__ float lane_xor1(float v) {
    // ds_swizzle BitMode xor=1: swap adjacent even/odd lanes
    return __int_as_float(__builtin_amdgcn_ds_swizzle(__float_as_int(v), 0x041F));
}
__device__ __forceinline__ float bperm(int addr_bytes, float v) {
    return __int_as_float(__builtin_amdgcn_ds_bpermute(addr_bytes, __float_as_int(v)));
}

// 2 lanes per hidden unit (A: gates i,f; B: gates g,o), 20 lanes per batch
// element, 3 elements per wave64 (lanes 60-63 idle). Per-lane weights: 68
// floats -> total live ~115 VGPRs, inside the allocator's 128-reg (4 waves/EU)
// tier, so weights stay genuinely register-resident (rounds 2-4 showed the
// allocator refuses ~170 live and re-streams weights from memory every step).
__global__ __attribute__((amdgpu_flat_work_group_size(64, 64), amdgpu_waves_per_eu(1, 4)))
void lstm2_kernel(const float* __restrict__ x,
                  const float* __restrict__ h0in, const float* __restrict__ c0in,
                  const float* __restrict__ Wih0, const float* __restrict__ Whh0,
                  const float* __restrict__ bih0, const float* __restrict__ bhh0,
                  const float* __restrict__ Wih1, const float* __restrict__ Whh1,
                  const float* __restrict__ bih1, const float* __restrict__ bhh1,
                  ushort* __restrict__ y /* bf16 bits, flat [T,B,H] */) {
    const int l     = threadIdx.x;          // 0..63
    const int e_loc = l / 20;               // 0..2 real, 3 = lanes 60-63
    const int pl    = l - e_loc * 20;       // 0..19
    const int u     = pl >> 1;              // unit 0..9
    const int gp    = pl & 1;               // 0: i,f   1: g,o
    const long b    = (long)blockIdx.x * 3 + e_loc;
    const bool active = (e_loc < 3) && (b < BATCH);
    const long b_eff  = (b < BATCH) ? b : (BATCH - 1);
    const int ebase4  = (e_loc * 20) * 4;   // byte base for bpermute

    // rows owned by this lane: r0 = u+20*gp (gate 2gp), r1 = r0+10 (gate 2gp+1)
    const int r0 = u + 20 * gp;
    const int r1 = r0 + 10;
    const float sc0 = gp ? TANH_SCALE : SIG_SCALE;  // gate 2gp:  i or g
    const float sc1 = SIG_SCALE;                    // gate 2gp+1: f or o
    const float alpha0 = gp ? 2.0f : 1.0f;          // act0 = alpha*rcp(..)+beta
    const float beta0  = gp ? -1.0f : 0.0f;

    // ---- per-lane weights (68 floats) ----
    float wx0a[2], wx0b[2], bs0a, bs0b, bs1a, bs1b;
    float wh0a[10], wh0b[10], wi1a[10], wi1b[10], wh1a[10], wh1b[10];
    wx0a[0] = Wih0[r0 * 2] * sc0;  wx0a[1] = Wih0[r0 * 2 + 1] * sc0;
    wx0b[0] = Wih0[r1 * 2] * sc1;  wx0b[1] = Wih0[r1 * 2 + 1] * sc1;
    bs0a = (bih0[r0] + bhh0[r0]) * sc0;
    bs0b = (bih0[r1] + bhh0[r1]) * sc1;
    bs1a = (bih1[r0] + bhh1[r0]) * sc0;
    bs1b = (bih1[r1] + bhh1[r1]) * sc1;
#pragma unroll
    for (int k = 0; k < 10; ++k) {
        wh0a[k] = Whh0[r0 * 10 + k] * sc0;
        wh0b[k] = Whh0[r1 * 10 + k] * sc1;
        wi1a[k] = Wih1[r0 * 10 + k] * sc0;
        wi1b[k] = Wih1[r1 * 10 + k] * sc1;
        wh1a[k] = Whh1[r0 * 10 + k] * sc0;
        wh1b[k] = Whh1[r1 * 10 + k] * sc1;
    }

    // ---- state ----
    float h0b[10], h1b[10];
#pragma unroll
    for (int k = 0; k < 10; ++k) {
        h0b[k] = h0in[b_eff * 10 + k];
        h1b[k] = h0in[(size_t)BATCH * 10 + b_eff * 10 + k];
    }
    float c0m = c0in[b_eff * 10 + u];                           // valid on A lanes
    float c1m = c0in[(size_t)BATCH * 10 + b_eff * 10 + u];

    float2 xv = *reinterpret_cast<const float2*>(&x[b_eff * 2]);

    for (int t = 0; t < SEQ; ++t) {
        const int tn = (t + 1 < SEQ) ? (t + 1) : t;
        const float2 xnext = *reinterpret_cast<const float2*>(&x[((size_t)tn * BATCH + b_eff) * 2]);

        // ================= layer 0 =================
        {
            float a0 = bs0a + wx0a[0] * xv.x, a0o = wx0a[1] * xv.y;
            float a1 = bs0b + wx0b[0] * xv.x, a1o = wx0b[1] * xv.y;
#pragma unroll
            for (int k = 0; k < 10; k += 2) {
                a0  += wh0a[k]     * h0b[k];
                a0o += wh0a[k + 1] * h0b[k + 1];
                a1  += wh0b[k]     * h0b[k];
                a1o += wh0b[k + 1] * h0b[k + 1];
            }
            a0 += a0o; a1 += a1o;
            const float act0 = alpha0 * fast_rcp(1.0f + fast_exp2(a0)) + beta0; // A: i, B: g
            const float act1 = fast_rcp(1.0f + fast_exp2(a1));                  // A: f, B: o
            const float act0x = lane_xor1(act0);           // A receives g
            const float cn = act1 * c0m + act0 * act0x;    // A: f*c + i*g
            c0m = cn;
            const float cr = lane_xor1(cn);                // B receives new c
            const float h0n = act1 * fast_tanh(cr);        // B: o*tanh(c)
#pragma unroll
            for (int k = 0; k < 10; ++k)
                h0b[k] = bperm(ebase4 + ((2 * k + 1) << 2), h0n);  // from B lanes
        }

        // ================= layer 1 =================
        float h1n;
        {
            float a0 = bs1a, a0o = 0.f, a1 = bs1b, a1o = 0.f;
#pragma unroll
            for (int k = 0; k < 10; k += 2) {
                a0  += wi1a[k]     * h0b[k]     + wh1a[k]     * h1b[k];
                a0o += wi1a[k + 1] * h0b[k + 1] + wh1a[k + 1] * h1b[k + 1];
                a1  += wi1b[k]     * h0b[k]     + wh1b[k]     * h1b[k];
                a1o += wi1b[k + 1] * h0b[k + 1] + wh1b[k + 1] * h1b[k + 1];
            }
            a0 += a0o; a1 += a1o;
            const float act0 = alpha0 * fast_rcp(1.0f + fast_exp2(a0)) + beta0;
            const float act1 = fast_rcp(1.0f + fast_exp2(a1));
            const float act0x = lane_xor1(act0);
            const float cn = act1 * c1m + act0 * act0x;
            c1m = cn;
            const float cr = lane_xor1(cn);
            h1n = act1 * fast_tanh(cr);                    // valid on B lanes
#pragma unroll
            for (int k = 0; k < 10; ++k)
                h1b[k] = bperm(ebase4 + ((2 * k + 1) << 2), h1n);
        }

        // store tanh(h1) from B lanes: y[t][b][u]
        if (active && gp)
            y[(size_t)t * BATCH * HID + b * 10 + u] = bf16bits(fast_tanh(h1n));
        xv = xnext;
    }
}

// Head: row b of tanh(y1).view(B,-1) is the contiguous flat range [b*800,(b+1)*800).
// 4 lanes per row, each dotting 200 contiguous bf16 elements, butterfly-reduced.
__global__ __launch_bounds__(256)
void head_kernel(const ushort* __restrict__ yflat, /* bf16 bits, 80*32768*10 */
                 const float* __restrict__ W1, const float* __restrict__ b1,
                 const float* __restrict__ W2, const float* __restrict__ b2,
                 float* __restrict__ out) {
    const int tid = blockIdx.x * blockDim.x + threadIdx.x;
    const int row = tid >> 2;
    const int sub = tid & 3;
    if (row >= BATCH) return;

    const ushort* yr = yflat + (size_t)row * 800 + sub * 200;
    const int kbase = sub * 200;
    float acc[10];
#pragma unroll
    for (int o = 0; o < 10; ++o) acc[o] = 0.f;

#pragma unroll 4
    for (int k0 = 0; k0 < 200; k0 += 8) {
        const uint4 q = *reinterpret_cast<const uint4*>(yr + k0);  // 16B aligned
        float yv[8];
        yv[0] = __uint_as_float(q.x << 16); yv[1] = __uint_as_float(q.x & 0xffff0000u);
        yv[2] = __uint_as_float(q.y << 16); yv[3] = __uint_as_float(q.y & 0xffff0000u);
        yv[4] = __uint_as_float(q.z << 16); yv[5] = __uint_as_float(q.z & 0xffff0000u);
        yv[6] = __uint_as_float(q.w << 16); yv[7] = __uint_as_float(q.w & 0xffff0000u);
#pragma unroll
        for (int uu = 0; uu < 8; ++uu) {
#pragma unroll
            for (int o = 0; o < 10; ++o) acc[o] += yv[uu] * W1[o * 800 + kbase + k0 + uu];
        }
    }

    // butterfly reduce across the 4 sub-lanes
#pragma unroll
    for (int o = 0; o < 10; ++o) {
        acc[o] += __shfl_xor(acc[o], 1, 64);
        acc[o] += __shfl_xor(acc[o], 2, 64);
    }

    float s[10];
#pragma unroll
    for (int o = 0; o < 10; ++o)
        s[o] = fast_rcp(1.0f + fast_exp2(SIG_SCALE * (acc[o] + b1[o])));

    // each sub-lane produces 10 of the 40 outputs
    const int jbase = sub * 10;
#pragma unroll
    for (int jj = 0; jj < 10; ++jj) {
        const int j = jbase + jj;
        float r = b2[j];
#pragma unroll
        for (int o = 0; o < 10; ++o) r += s[o] * W2[j * 10 + o];
        out[(size_t)row * 40 + j] = r;
    }
}

extern "C" void kernel_launch(void* const* d_in, const int* in_sizes, int n_in,
                              void* d_out, int out_size, void* d_ws, size_t ws_size,
                              hipStream_t stream) {
    const float* x    = (const float*)d_in[0];
    const float* h0   = (const float*)d_in[1];
    const float* c0   = (const float*)d_in[2];
    const float* Wih0 = (const float*)d_in[3];
    const float* Whh0 = (const float*)d_in[4];
    const float* bih0 = (const float*)d_in[5];
    const float* bhh0 = (const float*)d_in[6];
    const float* Wih1 = (const float*)d_in[7];
    const float* Whh1 = (const float*)d_in[8];
    const float* bih1 = (const float*)d_in[9];
    const float* bhh1 = (const float*)d_in[10];
    const float* W1   = (const float*)d_in[11];
    const float* b1   = (const float*)d_in[12];
    const float* W2   = (const float*)d_in[13];
    const float* b2   = (const float*)d_in[14];
    float* out = (float*)d_out;
    ushort* yws = (ushort*)d_ws;  // bf16 staging, 80*32768*10*2 = 52,428,800 bytes

    // 3 batch elements per 64-thread (1-wave) block, 20 lanes each
    const int grid_lstm = (BATCH + 2) / 3;   // 10923
    lstm2_kernel<<<grid_lstm, 64, 0, stream>>>(x, h0, c0, Wih0, Whh0, bih0, bhh0,
                                               Wih1, Whh1, bih1, bhh1, yws);
    head_kernel<<<(BATCH * 4) / 256, 256, 0, stream>>>(yws, W1, b1, W2, b2, out);
}

// Round 6
// 169.424 us; speedup vs baseline: 1.9621x; 1.9621x over previous
//
#include <hip/hip_runtime.h>
#include <hip/hip_fp16.h>

#define SEQ   80
#define BATCH 32768
#define HID   10

typedef unsigned int uint;
typedef unsigned short ushort;
typedef _Float16 f16;
typedef __attribute__((ext_vector_type(8))) _Float16 f16x8;
typedef __attribute__((ext_vector_type(2))) _Float16 f16x2;
typedef __attribute__((ext_vector_type(4))) float f32x4;

#define SIG_SCALE  (-1.44269504f)
#define TANH_SCALE (-2.88539008f)

__device__ __forceinline__ float fast_rcp(float x)  { return __builtin_amdgcn_rcpf(x); }
__device__ __forceinline__ float fast_exp2(float x) { return __builtin_amdgcn_exp2f(x); }
// Pre-scaled activations: a already multiplied by SIG_SCALE / TANH_SCALE.
__device__ __forceinline__ float sigp(float a)  { return fast_rcp(1.0f + fast_exp2(a)); }
__device__ __forceinline__ float tanhp(float a) { return 2.0f * fast_rcp(1.0f + fast_exp2(a)) - 1.0f; }
__device__ __forceinline__ float tanh_f(float x){ return tanhp(TANH_SCALE * x); }

union U4V { uint4 u; f16x8 v; };
union UH2 { uint u; f16x2 h; };
union HU  { f16 h; ushort s; };

// Full LSTM cell update for one unit, lane-local: d = pre-scaled (i,f,g,o).
__device__ __forceinline__ float lstm_unit(const f32x4 d, float& c) {
    const float ig = sigp(d[0]);
    const float fg = sigp(d[1]);
    const float gg = tanhp(d[2]);
    const float og = sigp(d[3]);
    c = fg * c + ig * gg;
    return og * tanh_f(c);
}

// D[gate_row, batch] = A[gate_row, k] * B[k, batch] via mfma_f32_16x16x32_f16.
// Gate rows unit-interleaved: row R = 4*u + {i,f,g,o}. 3 M-tiles (48 rows, 40
// real). D layout: lane l holds col n=l&15 (batch), rows (l>>4)*4+q -> all 4
// gates of unit u = 4*T + (l>>4) for batch l&15: c/h update is LANE-LOCAL.
// A (weights, 24 VGPR) and bias-C (24 VGPR) are loop-invariant MFMA operands.
// h-state lives in per-wave LDS rows [b][32 f16 slots]: 0..9=h0, 10..19=h1,
// 20..31=0; row stride 80B. Layer-1 B is a raw ds_read_b128; layer-0 patches
// x into slots 10,11 and zeroes the rest. Wave-synchronous (no barriers).
__global__ __launch_bounds__(256, 2)
void lstm2_mfma(const float* __restrict__ x, const float* __restrict__ h0in,
                const float* __restrict__ c0in,
                const float* __restrict__ Wih0, const float* __restrict__ Whh0,
                const float* __restrict__ bih0, const float* __restrict__ bhh0,
                const float* __restrict__ Wih1, const float* __restrict__ Whh1,
                const float* __restrict__ bih1, const float* __restrict__ bhh1,
                ushort* __restrict__ y /* f16 bits, flat [T,B,H] */) {
    __shared__ char lds_all[4 * 16 * 80];
    const int tid = threadIdx.x;
    const int l   = tid & 63;
    const int wv  = tid >> 6;
    char* lds   = lds_all + wv * (16 * 80);
    const int bl  = l & 15;     // batch column
    const int grp = l >> 4;     // row/k group
    const long b  = ((long)blockIdx.x * 4 + wv) * 16 + bl;

    // ---------- A fragments (weights) & bias C ----------
    // A layout: lane l holds A[row=l&15, k=grp*8+j], j ascending.
    f16x8 A0[3], A1[3];
    f32x4 bs0[3], bs1[3];
#pragma unroll
    for (int T = 0; T < 3; ++T) {
        const int R  = 16 * T + bl;          // A row for this lane
        const int u  = R >> 2, gi = R & 3;
        const bool vr = (R < 40);
        const int tr = gi * 10 + u;          // torch row (i|f|g|o chunks)
        const float sc = (gi == 2) ? TANH_SCALE : SIG_SCALE;
#pragma unroll
        for (int j = 0; j < 8; ++j) {
            const int k = grp * 8 + j;
            float w0 = 0.f, w1 = 0.f;
            if (vr) {
                if (k < 10)      w0 = Whh0[tr * 10 + k];        // x k=0..9: h0
                else if (k < 12) w0 = Wih0[tr * 2 + (k - 10)];  // k=10,11: x
                if (k < 10)      w1 = Wih1[tr * 10 + k];        // k=0..9: h0_new
                else if (k < 20) w1 = Whh1[tr * 10 + (k - 10)]; // k=10..19: h1
            }
            A0[T][j] = (f16)(w0 * sc);
            A1[T][j] = (f16)(w1 * sc);
        }
#pragma unroll
        for (int q = 0; q < 4; ++q) {        // bias in C/D layout
            const int Rc = 16 * T + grp * 4 + q;
            const int uc = Rc >> 2, gc = Rc & 3;
            const float scc = (gc == 2) ? TANH_SCALE : SIG_SCALE;
            const int trc = gc * 10 + uc;
            bs0[T][q] = (Rc < 40) ? (bih0[trc] + bhh0[trc]) * scc : 0.f;
            bs1[T][q] = (Rc < 40) ? (bih1[trc] + bhh1[trc]) * scc : 0.f;
        }
    }

    // ---------- c state (lane-local units u = 4T+grp) ----------
    float c0s[3], c1s[3];
#pragma unroll
    for (int T = 0; T < 3; ++T) {
        const int u = 4 * T + grp;
        const bool v = (u < 10);
        c0s[T] = v ? c0in[b * 10 + u] : 0.f;
        c1s[T] = v ? c0in[(size_t)BATCH * 10 + b * 10 + u] : 0.f;
    }

    // ---------- LDS init: zero my wave region, then write h state ----------
    {
        uint* p = (uint*)(lds) + l * 5;      // 64 lanes x 20B = 1280B
#pragma unroll
        for (int i = 0; i < 5; ++i) p[i] = 0u;
    }
    char* myrow = lds + bl * 80;
#pragma unroll
    for (int T = 0; T < 3; ++T) {
        const int u = 4 * T + grp;
        if (u < 10) {
            *(f16*)(myrow + u * 2)      = (f16)h0in[b * 10 + u];
            *(f16*)(myrow + 20 + u * 2) = (f16)h0in[(size_t)BATCH * 10 + b * 10 + u];
        }
    }

    float2 xv = *reinterpret_cast<const float2*>(&x[b * 2]);

    for (int t = 0; t < SEQ; ++t) {
        const int tn = (t + 1 < SEQ) ? t + 1 : t;
        const float2 xnext = *reinterpret_cast<const float2*>(&x[((size_t)tn * BATCH + b) * 2]);

        // ----- layer 0: B[k,n]: k=0..9 h0_{t-1}, k=10,11 x_t, rest 0 -----
        U4V r; r.u = *reinterpret_cast<const uint4*>(myrow + grp * 16);
        UH2 xp; xp.h[0] = (f16)xv.x; xp.h[1] = (f16)xv.y;
        U4V b0;
        b0.u.x = (grp < 2)  ? r.u.x : 0u;                       // k pairs (0,1)/(8,9)
        b0.u.y = (grp == 0) ? r.u.y : ((grp == 1) ? xp.u : 0u); // (2,3)/(10,11)=x
        b0.u.z = (grp == 0) ? r.u.z : 0u;
        b0.u.w = (grp == 0) ? r.u.w : 0u;

        f32x4 d0 = __builtin_amdgcn_mfma_f32_16x16x32_f16(A0[0], b0.v, bs0[0], 0, 0, 0);
        f32x4 d1 = __builtin_amdgcn_mfma_f32_16x16x32_f16(A0[1], b0.v, bs0[1], 0, 0, 0);
        f32x4 d2 = __builtin_amdgcn_mfma_f32_16x16x32_f16(A0[2], b0.v, bs0[2], 0, 0, 0);

        const float hA = lstm_unit(d0, c0s[0]);
        const float hB = lstm_unit(d1, c0s[1]);
        const float hC = lstm_unit(d2, c0s[2]);

        // scatter h0_new into slots u (wave-synchronous LDS, in-order)
        *(f16*)(myrow + grp * 2)       = (f16)hA;
        *(f16*)(myrow + (4 + grp) * 2) = (f16)hB;
        if (grp < 2) *(f16*)(myrow + (8 + grp) * 2) = (f16)hC;

        // ----- layer 1: B: k=0..9 h0_new, k=10..19 h1_{t-1}, k>=20 zeros -----
        U4V b1v; b1v.u = *reinterpret_cast<const uint4*>(myrow + grp * 16);

        d0 = __builtin_amdgcn_mfma_f32_16x16x32_f16(A1[0], b1v.v, bs1[0], 0, 0, 0);
        d1 = __builtin_amdgcn_mfma_f32_16x16x32_f16(A1[1], b1v.v, bs1[1], 0, 0, 0);
        d2 = __builtin_amdgcn_mfma_f32_16x16x32_f16(A1[2], b1v.v, bs1[2], 0, 0, 0);

        const float h1A = lstm_unit(d0, c1s[0]);
        const float h1B = lstm_unit(d1, c1s[1]);
        const float h1C = lstm_unit(d2, c1s[2]);

        // y = tanh(h1) as f16 bits, flat [T,B,H]
        ushort* yp = y + (size_t)t * BATCH * HID + b * HID;
        HU y0; y0.h = (f16)tanh_f(h1A); yp[grp] = y0.s;
        HU y1; y1.h = (f16)tanh_f(h1B); yp[4 + grp] = y1.s;
        if (grp < 2) { HU y2; y2.h = (f16)tanh_f(h1C); yp[8 + grp] = y2.s; }

        // h1_new into slots 10+u for next step
        *(f16*)(myrow + 20 + grp * 2)       = (f16)h1A;
        *(f16*)(myrow + 20 + (4 + grp) * 2) = (f16)h1B;
        if (grp < 2) *(f16*)(myrow + 20 + (8 + grp) * 2) = (f16)h1C;

        xv = xnext;
    }
}

// Head: out row r uses the contiguous flat range [r*800,(r+1)*800) of y.
// 4 lanes per row, each dotting 200 contiguous f16 elements, butterfly-reduced.
__global__ __launch_bounds__(256)
void head_kernel(const ushort* __restrict__ yflat, /* f16 bits, 80*32768*10 */
                 const float* __restrict__ W1, const float* __restrict__ b1,
                 const float* __restrict__ W2, const float* __restrict__ b2,
                 float* __restrict__ out) {
    const int tid = blockIdx.x * blockDim.x + threadIdx.x;
    const int row = tid >> 2;
    const int sub = tid & 3;
    if (row >= BATCH) return;

    const ushort* yr = yflat + (size_t)row * 800 + sub * 200;
    const int kbase = sub * 200;
    float acc[10];
#pragma unroll
    for (int o = 0; o < 10; ++o) acc[o] = 0.f;

#pragma unroll 4
    for (int k0 = 0; k0 < 200; k0 += 8) {
        U4V q; q.u = *reinterpret_cast<const uint4*>(yr + k0);  // 8 f16
        float yv[8];
#pragma unroll
        for (int e = 0; e < 8; ++e) yv[e] = (float)q.v[e];
#pragma unroll
        for (int uu = 0; uu < 8; ++uu) {
#pragma unroll
            for (int o = 0; o < 10; ++o)
                acc[o] += yv[uu] * W1[o * 800 + kbase + k0 + uu];
        }
    }

#pragma unroll
    for (int o = 0; o < 10; ++o) {
        acc[o] += __shfl_xor(acc[o], 1, 64);
        acc[o] += __shfl_xor(acc[o], 2, 64);
    }

    float s[10];
#pragma unroll
    for (int o = 0; o < 10; ++o)
        s[o] = fast_rcp(1.0f + fast_exp2(SIG_SCALE * (acc[o] + b1[o])));

    const int jbase = sub * 10;
#pragma unroll
    for (int jj = 0; jj < 10; ++jj) {
        const int j = jbase + jj;
        float r = b2[j];
#pragma unroll
        for (int o = 0; o < 10; ++o) r += s[o] * W2[j * 10 + o];
        out[(size_t)row * 40 + j] = r;
    }
}

extern "C" void kernel_launch(void* const* d_in, const int* in_sizes, int n_in,
                              void* d_out, int out_size, void* d_ws, size_t ws_size,
                              hipStream_t stream) {
    const float* x    = (const float*)d_in[0];
    const float* h0   = (const float*)d_in[1];
    const float* c0   = (const float*)d_in[2];
    const float* Wih0 = (const float*)d_in[3];
    const float* Whh0 = (const float*)d_in[4];
    const float* bih0 = (const float*)d_in[5];
    const float* bhh0 = (const float*)d_in[6];
    const float* Wih1 = (const float*)d_in[7];
    const float* Whh1 = (const float*)d_in[8];
    const float* bih1 = (const float*)d_in[9];
    const float* bhh1 = (const float*)d_in[10];
    const float* W1   = (const float*)d_in[11];
    const float* b1   = (const float*)d_in[12];
    const float* W2   = (const float*)d_in[13];
    const float* b2   = (const float*)d_in[14];
    float* out = (float*)d_out;
    ushort* yws = (ushort*)d_ws;  // f16 staging, 80*32768*10*2 = 52,428,800 B

    // 16 batch elements per wave, 4 waves per block: 32768/(16*4) = 512 blocks
    lstm2_mfma<<<512, 256, 0, stream>>>(x, h0, c0, Wih0, Whh0, bih0, bhh0,
                                        Wih1, Whh1, bih1, bhh1, yws);
    head_kernel<<<(BATCH * 4) / 256, 256, 0, stream>>>(yws, W1, b1, W2, b2, out);
}

// Round 7
// 118.143 us; speedup vs baseline: 2.8137x; 1.4341x over previous
//
#include <hip/hip_runtime.h>
#include <hip/hip_fp16.h>

#define SEQ   80
#define BATCH 32768
#define HID   10

typedef unsigned int uint;
typedef unsigned short ushort;
typedef _Float16 f16;
typedef __attribute__((ext_vector_type(8))) _Float16 f16x8;
typedef __attribute__((ext_vector_type(2))) _Float16 f16x2;
typedef __attribute__((ext_vector_type(4))) float f32x4;

#define SIG_SCALE  (-1.44269504f)
#define TANH_SCALE (-2.88539008f)

__device__ __forceinline__ float fast_rcp(float x)  { return __builtin_amdgcn_rcpf(x); }
__device__ __forceinline__ float fast_exp2(float x) { return __builtin_amdgcn_exp2f(x); }
__device__ __forceinline__ float sigp(float a)  { return fast_rcp(1.0f + fast_exp2(a)); }
__device__ __forceinline__ float tanhp(float a) { return 2.0f * fast_rcp(1.0f + fast_exp2(a)) - 1.0f; }
__device__ __forceinline__ float tanh_f(float x){ return tanhp(TANH_SCALE * x); }

union U4V { uint4 u; f16x8 v; };
union UH2 { uint u; f16x2 h; };
union HU  { f16 h; ushort s; };

__device__ __forceinline__ float lstm_unit(const f32x4 d, float& c) {
    const float ig = sigp(d[0]);
    const float fg = sigp(d[1]);
    const float gg = tanhp(d[2]);
    const float og = sigp(d[3]);
    c = fg * c + ig * gg;
    return og * tanh_f(c);
}

// Software-pipelined MFMA LSTM: body(t) = { L1(t) ; L0(t+1) } with both
// B-reads / MFMA trios issued together and the two trans chains interleaved.
// L1(t) depends on h0(t) (regs->LDS just written); L0(t+1) depends only on
// h0(t) + x(t+1) -> independent of L1(t)'s chain. h1 slots read by L0's b128
// are stale-but-masked (patched with x / zeros), so no false dependency.
__global__ __launch_bounds__(256, 2)
void lstm2_mfma(const float* __restrict__ x, const float* __restrict__ h0in,
                const float* __restrict__ c0in,
                const float* __restrict__ Wih0, const float* __restrict__ Whh0,
                const float* __restrict__ bih0, const float* __restrict__ bhh0,
                const float* __restrict__ Wih1, const float* __restrict__ Whh1,
                const float* __restrict__ bih1, const float* __restrict__ bhh1,
                ushort* __restrict__ y /* f16 bits, flat [T,B,H] */) {
    __shared__ char lds_all[4 * 16 * 80];
    const int tid = threadIdx.x;
    const int l   = tid & 63;
    const int wv  = tid >> 6;
    char* lds   = lds_all + wv * (16 * 80);
    const int bl  = l & 15;     // batch column
    const int grp = l >> 4;     // row/k group
    const long b  = ((long)blockIdx.x * 4 + wv) * 16 + bl;

    // ---------- A fragments (weights) & bias C ----------
    f16x8 A0[3], A1[3];
    f32x4 bs0[3], bs1[3];
#pragma unroll
    for (int T = 0; T < 3; ++T) {
        const int R  = 16 * T + bl;
        const int u  = R >> 2, gi = R & 3;
        const bool vr = (R < 40);
        const int tr = gi * 10 + u;
        const float sc = (gi == 2) ? TANH_SCALE : SIG_SCALE;
#pragma unroll
        for (int j = 0; j < 8; ++j) {
            const int k = grp * 8 + j;
            float w0 = 0.f, w1 = 0.f;
            if (vr) {
                if (k < 10)      w0 = Whh0[tr * 10 + k];
                else if (k < 12) w0 = Wih0[tr * 2 + (k - 10)];
                if (k < 10)      w1 = Wih1[tr * 10 + k];
                else if (k < 20) w1 = Whh1[tr * 10 + (k - 10)];
            }
            A0[T][j] = (f16)(w0 * sc);
            A1[T][j] = (f16)(w1 * sc);
        }
#pragma unroll
        for (int q = 0; q < 4; ++q) {
            const int Rc = 16 * T + grp * 4 + q;
            const int uc = Rc >> 2, gc = Rc & 3;
            const float scc = (gc == 2) ? TANH_SCALE : SIG_SCALE;
            const int trc = gc * 10 + uc;
            bs0[T][q] = (Rc < 40) ? (bih0[trc] + bhh0[trc]) * scc : 0.f;
            bs1[T][q] = (Rc < 40) ? (bih1[trc] + bhh1[trc]) * scc : 0.f;
        }
    }

    // ---------- c state ----------
    float c0s[3], c1s[3];
#pragma unroll
    for (int T = 0; T < 3; ++T) {
        const int u = 4 * T + grp;
        const bool v = (u < 10);
        c0s[T] = v ? c0in[b * 10 + u] : 0.f;
        c1s[T] = v ? c0in[(size_t)BATCH * 10 + b * 10 + u] : 0.f;
    }

    // ---------- LDS init ----------
    {
        uint* p = (uint*)(lds) + l * 5;
#pragma unroll
        for (int i = 0; i < 5; ++i) p[i] = 0u;
    }
    char* myrow = lds + bl * 80;
#pragma unroll
    for (int T = 0; T < 3; ++T) {
        const int u = 4 * T + grp;
        if (u < 10) {
            *(f16*)(myrow + u * 2)      = (f16)h0in[b * 10 + u];
            *(f16*)(myrow + 20 + u * 2) = (f16)h0in[(size_t)BATCH * 10 + b * 10 + u];
        }
    }

    // ---------- prologue: L0(0) ----------
    float h0nA, h0nB, h0nC;
    {
        const float2 xv = *reinterpret_cast<const float2*>(&x[b * 2]);
        U4V r0; r0.u = *reinterpret_cast<const uint4*>(myrow + (grp ? 16 : 0));
        UH2 xp; xp.h[0] = (f16)xv.x; xp.h[1] = (f16)xv.y;
        U4V b0v;
        b0v.u.x = (grp < 2)  ? r0.u.x : 0u;
        b0v.u.y = (grp == 0) ? r0.u.y : ((grp == 1) ? xp.u : 0u);
        b0v.u.z = (grp == 0) ? r0.u.z : 0u;
        b0v.u.w = (grp == 0) ? r0.u.w : 0u;
        f32x4 e0 = __builtin_amdgcn_mfma_f32_16x16x32_f16(A0[0], b0v.v, bs0[0], 0, 0, 0);
        f32x4 e1 = __builtin_amdgcn_mfma_f32_16x16x32_f16(A0[1], b0v.v, bs0[1], 0, 0, 0);
        f32x4 e2 = __builtin_amdgcn_mfma_f32_16x16x32_f16(A0[2], b0v.v, bs0[2], 0, 0, 0);
        h0nA = lstm_unit(e0, c0s[0]);
        h0nB = lstm_unit(e1, c0s[1]);
        h0nC = lstm_unit(e2, c0s[2]);
    }

    for (int t = 0; t < SEQ; ++t) {
        const int tn = (t + 1 < SEQ) ? t + 1 : t;
        const float2 xnext = *reinterpret_cast<const float2*>(&x[((size_t)tn * BATCH + b) * 2]);

        // publish h0(t)
        *(f16*)(myrow + grp * 2)       = (f16)h0nA;
        *(f16*)(myrow + (4 + grp) * 2) = (f16)h0nB;
        if (grp < 2) *(f16*)(myrow + (8 + grp) * 2) = (f16)h0nC;

        // both B-reads together
        U4V r1; r1.u = *reinterpret_cast<const uint4*>(myrow + grp * 16);          // L1(t)
        U4V r0; r0.u = *reinterpret_cast<const uint4*>(myrow + (grp ? 16 : 0));    // L0(t+1)

        UH2 xp; xp.h[0] = (f16)xnext.x; xp.h[1] = (f16)xnext.y;
        U4V b0v;
        b0v.u.x = (grp < 2)  ? r0.u.x : 0u;
        b0v.u.y = (grp == 0) ? r0.u.y : ((grp == 1) ? xp.u : 0u);
        b0v.u.z = (grp == 0) ? r0.u.z : 0u;
        b0v.u.w = (grp == 0) ? r0.u.w : 0u;

        // both MFMA trios
        f32x4 d0 = __builtin_amdgcn_mfma_f32_16x16x32_f16(A1[0], r1.v, bs1[0], 0, 0, 0);
        f32x4 d1 = __builtin_amdgcn_mfma_f32_16x16x32_f16(A1[1], r1.v, bs1[1], 0, 0, 0);
        f32x4 d2 = __builtin_amdgcn_mfma_f32_16x16x32_f16(A1[2], r1.v, bs1[2], 0, 0, 0);
        f32x4 e0 = __builtin_amdgcn_mfma_f32_16x16x32_f16(A0[0], b0v.v, bs0[0], 0, 0, 0);
        f32x4 e1 = __builtin_amdgcn_mfma_f32_16x16x32_f16(A0[1], b0v.v, bs0[1], 0, 0, 0);
        f32x4 e2 = __builtin_amdgcn_mfma_f32_16x16x32_f16(A0[2], b0v.v, bs0[2], 0, 0, 0);

        // two independent trans chains (scheduler interleaves)
        const float h1A = lstm_unit(d0, c1s[0]);
        const float h1B = lstm_unit(d1, c1s[1]);
        const float h1C = lstm_unit(d2, c1s[2]);
        h0nA = lstm_unit(e0, c0s[0]);
        h0nB = lstm_unit(e1, c0s[1]);
        h0nC = lstm_unit(e2, c0s[2]);

        // publish h1(t) for next iteration's r1
        *(f16*)(myrow + 20 + grp * 2)       = (f16)h1A;
        *(f16*)(myrow + 20 + (4 + grp) * 2) = (f16)h1B;
        if (grp < 2) *(f16*)(myrow + 20 + (8 + grp) * 2) = (f16)h1C;

        // y = tanh(h1), f16 bits, flat [T,B,H]
        ushort* yp = y + (size_t)t * BATCH * HID + b * HID;
        HU y0; y0.h = (f16)tanh_f(h1A); yp[grp] = y0.s;
        HU y1; y1.h = (f16)tanh_f(h1B); yp[4 + grp] = y1.s;
        if (grp < 2) { HU y2; y2.h = (f16)tanh_f(h1C); yp[8 + grp] = y2.s; }
    }
}

// Head as MFMA GEMM: D[o<=16 rows, 16 batch] += A(W1 f16)[o,k] * B(Y^T)[k,n],
// 25 k-chunks of 32. B-frag = raw b128 from staged y rows; A-frag = 8 f32
// W1 loads converted in-flight (W1 is 32KB, L2-hot). Epilogue: sigmoid ->
// small W2 (40x10) VALU GEMM via per-wave LDS redistribution (wave-sync).
__global__ __launch_bounds__(256, 2)
void head_mfma(const ushort* __restrict__ yflat, /* f16 bits, [32768][800] */
               const float* __restrict__ W1, const float* __restrict__ b1,
               const float* __restrict__ W2, const float* __restrict__ b2,
               float* __restrict__ out) {
    __shared__ float sbuf[4][16][12];
    const int tid = threadIdx.x;
    const int l   = tid & 63;
    const int wv  = tid >> 6;
    const int bl  = l & 15;
    const int grp = l >> 4;
    const long row = ((long)blockIdx.x * 4 + wv) * 16 + bl;

    const ushort* yrow = yflat + row * 800;
    const float*  arow = W1 + (size_t)bl * 800;   // A row = bl (o index), 0 if bl>=10
    const bool avalid = (bl < 10);

    f32x4 acc = {0.f, 0.f, 0.f, 0.f};
#pragma unroll 5
    for (int c = 0; c < 25; ++c) {
        U4V bv; bv.u = *reinterpret_cast<const uint4*>(yrow + c * 32 + grp * 8);
        const float4 w0 = *reinterpret_cast<const float4*>(arow + c * 32 + grp * 8);
        const float4 w1 = *reinterpret_cast<const float4*>(arow + c * 32 + grp * 8 + 4);
        f16x8 af;
        af[0] = (f16)(avalid ? w0.x : 0.f); af[1] = (f16)(avalid ? w0.y : 0.f);
        af[2] = (f16)(avalid ? w0.z : 0.f); af[3] = (f16)(avalid ? w0.w : 0.f);
        af[4] = (f16)(avalid ? w1.x : 0.f); af[5] = (f16)(avalid ? w1.y : 0.f);
        af[6] = (f16)(avalid ? w1.z : 0.f); af[7] = (f16)(avalid ? w1.w : 0.f);
        acc = __builtin_amdgcn_mfma_f32_16x16x32_f16(af, bv.v, acc, 0, 0, 0);
    }

    // acc[q] = dot for output o = grp*4+q, batch `row`. Sigmoid + publish.
#pragma unroll
    for (int q = 0; q < 4; ++q) {
        const int o = grp * 4 + q;
        if (o < 10)
            sbuf[wv][bl][o] = sigp(SIG_SCALE * (acc[q] + b1[o]));
    }
    // wave-synchronous: same wave wrote all 10 entries for each bl it owns

    float s[10];
#pragma unroll
    for (int o = 0; o < 10; ++o) s[o] = sbuf[wv][bl][o];

    // lane computes outputs j = grp*10 .. grp*10+9 for batch `row`
    float* op = out + row * 40 + grp * 10;
#pragma unroll
    for (int jj = 0; jj < 10; ++jj) {
        const int j = grp * 10 + jj;
        float r = b2[j];
#pragma unroll
        for (int o = 0; o < 10; ++o) r += s[o] * W2[j * 10 + o];
        op[jj] = r;
    }
}

extern "C" void kernel_launch(void* const* d_in, const int* in_sizes, int n_in,
                              void* d_out, int out_size, void* d_ws, size_t ws_size,
                              hipStream_t stream) {
    const float* x    = (const float*)d_in[0];
    const float* h0   = (const float*)d_in[1];
    const float* c0   = (const float*)d_in[2];
    const float* Wih0 = (const float*)d_in[3];
    const float* Whh0 = (const float*)d_in[4];
    const float* bih0 = (const float*)d_in[5];
    const float* bhh0 = (const float*)d_in[6];
    const float* Wih1 = (const float*)d_in[7];
    const float* Whh1 = (const float*)d_in[8];
    const float* bih1 = (const float*)d_in[9];
    const float* bhh1 = (const float*)d_in[10];
    const float* W1   = (const float*)d_in[11];
    const float* b1   = (const float*)d_in[12];
    const float* W2   = (const float*)d_in[13];
    const float* b2   = (const float*)d_in[14];
    float* out = (float*)d_out;
    ushort* yws = (ushort*)d_ws;  // f16 staging, 80*32768*10*2 = 52,428,800 B

    lstm2_mfma<<<512, 256, 0, stream>>>(x, h0, c0, Wih0, Whh0, bih0, bhh0,
                                        Wih1, Whh1, bih1, bhh1, yws);
    head_mfma<<<512, 256, 0, stream>>>(yws, W1, b1, W2, b2, out);
}

// Round 8
// 104.519 us; speedup vs baseline: 3.1805x; 1.1303x over previous
//
#include <hip/hip_runtime.h>
#include <hip/hip_fp16.h>

#define SEQ   80
#define BATCH 32768
#define HID   10

typedef unsigned int uint;
typedef unsigned short ushort;
typedef _Float16 f16;
typedef __attribute__((ext_vector_type(8))) _Float16 f16x8;
typedef __attribute__((ext_vector_type(2))) _Float16 f16x2;
typedef __attribute__((ext_vector_type(4))) float f32x4;

#define SIG_SCALE  (-1.44269504f)
#define TANH_SCALE (-2.88539008f)

__device__ __forceinline__ float fast_rcp(float x)  { return __builtin_amdgcn_rcpf(x); }
__device__ __forceinline__ float fast_exp2(float x) { return __builtin_amdgcn_exp2f(x); }
__device__ __forceinline__ float sigp(float a)  { return fast_rcp(1.0f + fast_exp2(a)); }
__device__ __forceinline__ float tanhp(float a) { return 2.0f * fast_rcp(1.0f + fast_exp2(a)) - 1.0f; }
__device__ __forceinline__ float tanh_f(float x){ return tanhp(TANH_SCALE * x); }

union U4V { uint4 u; f16x8 v; };
union UH2 { uint u; f16x2 h; };
union HU  { f16 h; ushort s; };

// Merged-rcp LSTM cell: 5 exp2 + 3 rcp (was 5+5).
// d = pre-scaled (i,f,g,o): sigmoid rows scaled by SIG_SCALE, g by TANH_SCALE.
// i*g = (1-Eg) * rcp((1+Ei)(1+Eg));  h = o*tanh(c) = (1-Ec)*rcp((1+Eo)(1+Ec)).
__device__ __forceinline__ float lstm_unit(const f32x4 d, float& c) {
    const float Ei = fast_exp2(d[0]);
    const float Ef = fast_exp2(d[1]);
    const float Eg = fast_exp2(d[2]);
    const float Eo = fast_exp2(d[3]);
    const float Rf  = fast_rcp(1.0f + Ef);
    const float Rig = fast_rcp((1.0f + Ei) * (1.0f + Eg));
    c = c * Rf + (1.0f - Eg) * Rig;
    const float Ec = fast_exp2(TANH_SCALE * c);
    const float Rh = fast_rcp((1.0f + Eo) * (1.0f + Ec));
    return (1.0f - Ec) * Rh;
}

// Software-pipelined MFMA LSTM (round-7 structure) + x prefetched TWO bodies
// ahead (round 7 exposed the x load latency in the per-step chain) + raw h1
// staged to y (tanh moved into the head kernel).
__global__ __launch_bounds__(256, 2)
void lstm2_mfma(const float* __restrict__ x, const float* __restrict__ h0in,
                const float* __restrict__ c0in,
                const float* __restrict__ Wih0, const float* __restrict__ Whh0,
                const float* __restrict__ bih0, const float* __restrict__ bhh0,
                const float* __restrict__ Wih1, const float* __restrict__ Whh1,
                const float* __restrict__ bih1, const float* __restrict__ bhh1,
                ushort* __restrict__ y /* f16 bits of h1 (pre-tanh), [T,B,H] */) {
    __shared__ char lds_all[4 * 16 * 80];
    const int tid = threadIdx.x;
    const int l   = tid & 63;
    const int wv  = tid >> 6;
    char* lds   = lds_all + wv * (16 * 80);
    const int bl  = l & 15;     // batch column
    const int grp = l >> 4;     // row/k group
    const long b  = ((long)blockIdx.x * 4 + wv) * 16 + bl;

    // ---------- A fragments (weights) & bias C ----------
    f16x8 A0[3], A1[3];
    f32x4 bs0[3], bs1[3];
#pragma unroll
    for (int T = 0; T < 3; ++T) {
        const int R  = 16 * T + bl;
        const int u  = R >> 2, gi = R & 3;
        const bool vr = (R < 40);
        const int tr = gi * 10 + u;
        const float sc = (gi == 2) ? TANH_SCALE : SIG_SCALE;
#pragma unroll
        for (int j = 0; j < 8; ++j) {
            const int k = grp * 8 + j;
            float w0 = 0.f, w1 = 0.f;
            if (vr) {
                if (k < 10)      w0 = Whh0[tr * 10 + k];
                else if (k < 12) w0 = Wih0[tr * 2 + (k - 10)];
                if (k < 10)      w1 = Wih1[tr * 10 + k];
                else if (k < 20) w1 = Whh1[tr * 10 + (k - 10)];
            }
            A0[T][j] = (f16)(w0 * sc);
            A1[T][j] = (f16)(w1 * sc);
        }
#pragma unroll
        for (int q = 0; q < 4; ++q) {
            const int Rc = 16 * T + grp * 4 + q;
            const int uc = Rc >> 2, gc = Rc & 3;
            const float scc = (gc == 2) ? TANH_SCALE : SIG_SCALE;
            const int trc = gc * 10 + uc;
            bs0[T][q] = (Rc < 40) ? (bih0[trc] + bhh0[trc]) * scc : 0.f;
            bs1[T][q] = (Rc < 40) ? (bih1[trc] + bhh1[trc]) * scc : 0.f;
        }
    }

    // ---------- c state ----------
    float c0s[3], c1s[3];
#pragma unroll
    for (int T = 0; T < 3; ++T) {
        const int u = 4 * T + grp;
        const bool v = (u < 10);
        c0s[T] = v ? c0in[b * 10 + u] : 0.f;
        c1s[T] = v ? c0in[(size_t)BATCH * 10 + b * 10 + u] : 0.f;
    }

    // ---------- LDS init ----------
    {
        uint* p = (uint*)(lds) + l * 5;
#pragma unroll
        for (int i = 0; i < 5; ++i) p[i] = 0u;
    }
    char* myrow = lds + bl * 80;
#pragma unroll
    for (int T = 0; T < 3; ++T) {
        const int u = 4 * T + grp;
        if (u < 10) {
            *(f16*)(myrow + u * 2)      = (f16)h0in[b * 10 + u];
            *(f16*)(myrow + 20 + u * 2) = (f16)h0in[(size_t)BATCH * 10 + b * 10 + u];
        }
    }

    // ---------- prologue: L0(0) with x(0) ----------
    float h0nA, h0nB, h0nC;
    {
        const float2 xv = *reinterpret_cast<const float2*>(&x[b * 2]);
        U4V r0; r0.u = *reinterpret_cast<const uint4*>(myrow + (grp ? 16 : 0));
        UH2 xp; xp.h[0] = (f16)xv.x; xp.h[1] = (f16)xv.y;
        U4V b0v;
        b0v.u.x = (grp < 2)  ? r0.u.x : 0u;
        b0v.u.y = (grp == 0) ? r0.u.y : ((grp == 1) ? xp.u : 0u);
        b0v.u.z = (grp == 0) ? r0.u.z : 0u;
        b0v.u.w = (grp == 0) ? r0.u.w : 0u;
        f32x4 e0 = __builtin_amdgcn_mfma_f32_16x16x32_f16(A0[0], b0v.v, bs0[0], 0, 0, 0);
        f32x4 e1 = __builtin_amdgcn_mfma_f32_16x16x32_f16(A0[1], b0v.v, bs0[1], 0, 0, 0);
        f32x4 e2 = __builtin_amdgcn_mfma_f32_16x16x32_f16(A0[2], b0v.v, bs0[2], 0, 0, 0);
        h0nA = lstm_unit(e0, c0s[0]);
        h0nB = lstm_unit(e1, c0s[1]);
        h0nC = lstm_unit(e2, c0s[2]);
    }

    // x(1): consumed in body(0); body(t) issues load of x(t+2).
    float2 xf = *reinterpret_cast<const float2*>(&x[((size_t)(SEQ > 1 ? 1 : 0) * BATCH + b) * 2]);

    for (int t = 0; t < SEQ; ++t) {
        const int tp = (t + 2 < SEQ) ? t + 2 : SEQ - 1;
        const float2 xpre = *reinterpret_cast<const float2*>(&x[((size_t)tp * BATCH + b) * 2]);

        // publish h0(t)
        *(f16*)(myrow + grp * 2)       = (f16)h0nA;
        *(f16*)(myrow + (4 + grp) * 2) = (f16)h0nB;
        if (grp < 2) *(f16*)(myrow + (8 + grp) * 2) = (f16)h0nC;

        // both B-reads together
        U4V r1; r1.u = *reinterpret_cast<const uint4*>(myrow + grp * 16);          // L1(t)
        U4V r0; r0.u = *reinterpret_cast<const uint4*>(myrow + (grp ? 16 : 0));    // L0(t+1)

        UH2 xp; xp.h[0] = (f16)xf.x; xp.h[1] = (f16)xf.y;   // x(t+1), loaded last body
        U4V b0v;
        b0v.u.x = (grp < 2)  ? r0.u.x : 0u;
        b0v.u.y = (grp == 0) ? r0.u.y : ((grp == 1) ? xp.u : 0u);
        b0v.u.z = (grp == 0) ? r0.u.z : 0u;
        b0v.u.w = (grp == 0) ? r0.u.w : 0u;

        // both MFMA trios
        f32x4 d0 = __builtin_amdgcn_mfma_f32_16x16x32_f16(A1[0], r1.v, bs1[0], 0, 0, 0);
        f32x4 d1 = __builtin_amdgcn_mfma_f32_16x16x32_f16(A1[1], r1.v, bs1[1], 0, 0, 0);
        f32x4 d2 = __builtin_amdgcn_mfma_f32_16x16x32_f16(A1[2], r1.v, bs1[2], 0, 0, 0);
        f32x4 e0 = __builtin_amdgcn_mfma_f32_16x16x32_f16(A0[0], b0v.v, bs0[0], 0, 0, 0);
        f32x4 e1 = __builtin_amdgcn_mfma_f32_16x16x32_f16(A0[1], b0v.v, bs0[1], 0, 0, 0);
        f32x4 e2 = __builtin_amdgcn_mfma_f32_16x16x32_f16(A0[2], b0v.v, bs0[2], 0, 0, 0);

        // two independent trans chains
        const float h1A = lstm_unit(d0, c1s[0]);
        const float h1B = lstm_unit(d1, c1s[1]);
        const float h1C = lstm_unit(d2, c1s[2]);
        h0nA = lstm_unit(e0, c0s[0]);
        h0nB = lstm_unit(e1, c0s[1]);
        h0nC = lstm_unit(e2, c0s[2]);

        // publish h1(t); y gets the SAME f16 bits (raw h1, tanh applied in head)
        HU hA; hA.h = (f16)h1A;
        HU hB; hB.h = (f16)h1B;
        HU hC; hC.h = (f16)h1C;
        *(f16*)(myrow + 20 + grp * 2)       = hA.h;
        *(f16*)(myrow + 20 + (4 + grp) * 2) = hB.h;
        if (grp < 2) *(f16*)(myrow + 20 + (8 + grp) * 2) = hC.h;

        ushort* yp = y + (size_t)t * BATCH * HID + b * HID;
        yp[grp] = hA.s;
        yp[4 + grp] = hB.s;
        if (grp < 2) yp[8 + grp] = hC.s;

        xf = xpre;
    }
}

// Head as MFMA GEMM over tanh(y): D[o,16 batch] += A(W1 f16)[o,k]*B[k,n],
// 25 k-chunks of 32; tanh applied to the staged raw-h1 before the MFMA.
__global__ __launch_bounds__(256, 2)
void head_mfma(const ushort* __restrict__ yflat, /* f16 bits of h1, [32768][800] */
               const float* __restrict__ W1, const float* __restrict__ b1,
               const float* __restrict__ W2, const float* __restrict__ b2,
               float* __restrict__ out) {
    __shared__ float sbuf[4][16][12];
    const int tid = threadIdx.x;
    const int l   = tid & 63;
    const int wv  = tid >> 6;
    const int bl  = l & 15;
    const int grp = l >> 4;
    const long row = ((long)blockIdx.x * 4 + wv) * 16 + bl;

    const ushort* yrow = yflat + row * 800;
    // Clamp A-row pointer (no OOB); garbage D rows 10-15 are never read, so no
    // zero-masking of A needed.
    const float* arow = W1 + (size_t)(bl < 10 ? bl : 9) * 800;

    f32x4 acc = {0.f, 0.f, 0.f, 0.f};
#pragma unroll 5
    for (int c = 0; c < 25; ++c) {
        U4V bv; bv.u = *reinterpret_cast<const uint4*>(yrow + c * 32 + grp * 8);
        f16x8 tv;
#pragma unroll
        for (int e = 0; e < 8; ++e)
            tv[e] = (f16)tanh_f((float)bv.v[e]);
        const float4 w0 = *reinterpret_cast<const float4*>(arow + c * 32 + grp * 8);
        const float4 w1 = *reinterpret_cast<const float4*>(arow + c * 32 + grp * 8 + 4);
        f16x8 af;
        af[0] = (f16)w0.x; af[1] = (f16)w0.y; af[2] = (f16)w0.z; af[3] = (f16)w0.w;
        af[4] = (f16)w1.x; af[5] = (f16)w1.y; af[6] = (f16)w1.z; af[7] = (f16)w1.w;
        acc = __builtin_amdgcn_mfma_f32_16x16x32_f16(af, tv, acc, 0, 0, 0);
    }

    // acc[q] = dot for output o = grp*4+q, batch `row`. Sigmoid + publish.
#pragma unroll
    for (int q = 0; q < 4; ++q) {
        const int o = grp * 4 + q;
        if (o < 10)
            sbuf[wv][bl][o] = sigp(SIG_SCALE * (acc[q] + b1[o]));
    }
    // wave-synchronous redistribution

    float s[10];
#pragma unroll
    for (int o = 0; o < 10; ++o) s[o] = sbuf[wv][bl][o];

    float* op = out + row * 40 + grp * 10;
#pragma unroll
    for (int jj = 0; jj < 10; ++jj) {
        const int j = grp * 10 + jj;
        float r = b2[j];
#pragma unroll
        for (int o = 0; o < 10; ++o) r += s[o] * W2[j * 10 + o];
        op[jj] = r;
    }
}

extern "C" void kernel_launch(void* const* d_in, const int* in_sizes, int n_in,
                              void* d_out, int out_size, void* d_ws, size_t ws_size,
                              hipStream_t stream) {
    const float* x    = (const float*)d_in[0];
    const float* h0   = (const float*)d_in[1];
    const float* c0   = (const float*)d_in[2];
    const float* Wih0 = (const float*)d_in[3];
    const float* Whh0 = (const float*)d_in[4];
    const float* bih0 = (const float*)d_in[5];
    const float* bhh0 = (const float*)d_in[6];
    const float* Wih1 = (const float*)d_in[7];
    const float* Whh1 = (const float*)d_in[8];
    const float* bih1 = (const float*)d_in[9];
    const float* bhh1 = (const float*)d_in[10];
    const float* W1   = (const float*)d_in[11];
    const float* b1   = (const float*)d_in[12];
    const float* W2   = (const float*)d_in[13];
    const float* b2   = (const float*)d_in[14];
    float* out = (float*)d_out;
    ushort* yws = (ushort*)d_ws;  // f16 staging (raw h1), 80*32768*10*2 B

    lstm2_mfma<<<512, 256, 0, stream>>>(x, h0, c0, Wih0, Whh0, bih0, bhh0,
                                        Wih1, Whh1, bih1, bhh1, yws);
    head_mfma<<<512, 256, 0, stream>>>(yws, W1, b1, W2, b2, out);
}